// Round 4
// baseline (1669.271 us; speedup 1.0000x reference)
//
#include <hip/hip_runtime.h>
#include <math.h>

#define S_LEN 2048
#define BATCH 2
#define NH 16
#define NKV 4
#define DKQ 128
#define DVV 128
#define HID 2048
#define QKV_DIM 3072
#define M_TOK 4096

typedef _Float16 halfx8 __attribute__((ext_vector_type(8)));
typedef float floatx4 __attribute__((ext_vector_type(4)));

#define AS1 __attribute__((address_space(1)))
#define AS3 __attribute__((address_space(3)))
#define GLD16(gp, lp) __builtin_amdgcn_global_load_lds((AS1 const void*)(gp), (AS3 void*)(lp), 16, 0, 0)
#define MFMA16(a, b, c) __builtin_amdgcn_mfma_f32_16x16x32_f16(a, b, c, 0, 0, 0)

__device__ __forceinline__ float sigmoidf_(float x) { return 1.f / (1.f + __expf(-x)); }

// ---------------- f32 -> f16 convert (8 elems/thread) ----------------
__global__ __launch_bounds__(256) void cvt_f16(const float* __restrict__ in,
                                               _Float16* __restrict__ out, int n8) {
  int i = blockIdx.x * 256 + threadIdx.x;
  if (i >= n8) return;
  const float4* p = (const float4*)in;
  float4 a = p[2 * (size_t)i], b = p[2 * (size_t)i + 1];
  halfx8 o;
  o[0] = (_Float16)a.x; o[1] = (_Float16)a.y; o[2] = (_Float16)a.z; o[3] = (_Float16)a.w;
  o[4] = (_Float16)b.x; o[5] = (_Float16)b.y; o[6] = (_Float16)b.z; o[7] = (_Float16)b.w;
  *(halfx8*)(out + (size_t)i * 8) = o;
}

// ---------------- fp16 MFMA GEMM NT: C[M,N] f32 = A[M,K] * B[N,K]^T ----------------
__global__ __launch_bounds__(256) void gemm_bt_f16(const _Float16* __restrict__ A,
                                                   const _Float16* __restrict__ B,
                                                   float* __restrict__ C,
                                                   int M, int N, int K) {
  __shared__ _Float16 As[128 * 32];
  __shared__ _Float16 Bs[128 * 32];
  int bm = blockIdx.y * 128, bn = blockIdx.x * 128;
  int tid = threadIdx.x;
  int w = tid >> 6, l = tid & 63;
  int wm = (w & 1) * 64, wn = (w >> 1) * 64;
  int lrow = l & 15, lk8 = (l >> 4) * 8;

  floatx4 zero = {0.f, 0.f, 0.f, 0.f};
  floatx4 acc[4][4];
#pragma unroll
  for (int i = 0; i < 4; ++i)
#pragma unroll
    for (int j = 0; j < 4; ++j) acc[i][j] = zero;

  const _Float16* ga = A + (size_t)(bm + (tid >> 2)) * K + (tid & 3) * 8;
  const _Float16* gb = B + (size_t)(bn + (tid >> 2)) * K + (tid & 3) * 8;
  _Float16* lA = As + w * 512;
  _Float16* lB = Bs + w * 512;

  for (int k0 = 0; k0 < K; k0 += 32) {
    GLD16(ga + k0, lA);
    GLD16(ga + k0 + (size_t)64 * K, lA + 2048);
    GLD16(gb + k0, lB);
    GLD16(gb + k0 + (size_t)64 * K, lB + 2048);
    __syncthreads();
    halfx8 af[4], bf_[4];
#pragma unroll
    for (int mi = 0; mi < 4; ++mi)
      af[mi] = *(const halfx8*)&As[(wm + mi * 16 + lrow) * 32 + lk8];
#pragma unroll
    for (int ni = 0; ni < 4; ++ni)
      bf_[ni] = *(const halfx8*)&Bs[(wn + ni * 16 + lrow) * 32 + lk8];
#pragma unroll
    for (int mi = 0; mi < 4; ++mi)
#pragma unroll
      for (int ni = 0; ni < 4; ++ni)
        acc[mi][ni] = MFMA16(af[mi], bf_[ni], acc[mi][ni]);
    __syncthreads();
  }
  int r0 = (l >> 4) * 4;
#pragma unroll
  for (int mi = 0; mi < 4; ++mi)
#pragma unroll
    for (int ni = 0; ni < 4; ++ni) {
      int col = bn + wn + ni * 16 + lrow;
#pragma unroll
      for (int r = 0; r < 4; ++r)
        C[(size_t)(bm + wm + mi * 16 + r0 + r) * N + col] = acc[mi][ni][r];
    }
}

// ---------------- gk/b projections -> glog [B,H,S] (= logsigmoid/16), beta [B,H,S] ----------------
__global__ __launch_bounds__(256) void gkb_kernel(const float* __restrict__ X,
                                                  const float* __restrict__ gk_w,
                                                  const float* __restrict__ b_w,
                                                  float* __restrict__ glog,
                                                  float* __restrict__ be) {
  __shared__ float xs[16][260];
  __shared__ float ws[32][260];
  int tid = threadIdx.x;
  int m0 = blockIdx.x * 16;
  int tl = tid >> 4, n0 = tid & 15;
  float acc0 = 0.f, acc1 = 0.f;
  for (int k0 = 0; k0 < HID; k0 += 256) {
#pragma unroll
    for (int i = 0; i < 4; ++i) {
      int F = i * 256 + tid;
      int r = F >> 6, c4 = (F & 63) * 4;
      *(float4*)&xs[r][c4] = *(const float4*)&X[(size_t)(m0 + r) * HID + k0 + c4];
    }
#pragma unroll
    for (int i = 0; i < 8; ++i) {
      int F = i * 256 + tid;
      int r = F >> 6, c4 = (F & 63) * 4;
      const float* src = (r < 16) ? (gk_w + (size_t)r * HID) : (b_w + (size_t)(r - 16) * HID);
      *(float4*)&ws[r][c4] = *(const float4*)&src[k0 + c4];
    }
    __syncthreads();
#pragma unroll 16
    for (int k = 0; k < 256; k += 4) {
      float4 a = *(const float4*)&xs[tl][k];
      float4 w0 = *(const float4*)&ws[n0][k];
      float4 w1 = *(const float4*)&ws[n0 + 16][k];
      acc0 += a.x * w0.x + a.y * w0.y + a.z * w0.z + a.w * w0.w;
      acc1 += a.x * w1.x + a.y * w1.y + a.z * w1.z + a.w * w1.w;
    }
    __syncthreads();
  }
  int m = m0 + tl, b = m >> 11, s = m & (S_LEN - 1);
  float z = acc0;
  float ls = (z >= 0.f) ? -log1pf(expf(-z)) : (z - log1pf(expf(z)));
  size_t oi = (size_t)(b * NH + n0) * S_LEN + s;
  glog[oi] = ls * 0.0625f;
  be[oi] = sigmoidf_(acc1);
}

// ---------------- causal dwconv(K=4)+SiLU, l2norm(q,k), q scale ----------------
__global__ __launch_bounds__(256) void conv_kernel(const float* __restrict__ qkv,
                                                   const float* __restrict__ conv_w,
                                                   float* __restrict__ qn,
                                                   float* __restrict__ kn,
                                                   float* __restrict__ vn) {
  __shared__ float ys[QKV_DIM];
  __shared__ float sc[20];
  int m = blockIdx.x;
  int b = m >> 11, s = m & (S_LEN - 1);
  int tid = threadIdx.x;
  for (int c = tid; c < QKV_DIM; c += 256) {
    float acc = 0.f;
#pragma unroll
    for (int i = 0; i < 4; ++i) {
      int si = s - 3 + i;
      if (si >= 0) acc += conv_w[c * 4 + i] * qkv[(size_t)(b * S_LEN + si) * QKV_DIM + c];
    }
    ys[c] = acc * (1.f / (1.f + __expf(-acc)));  // SiLU
  }
  __syncthreads();
  int wv = tid >> 6, lane = tid & 63;
  for (int ch = wv; ch < 20; ch += 4) {
    int base = (ch < 16) ? ch * 128 : 2048 + (ch - 16) * 128;
    float x0 = ys[base + lane], x1 = ys[base + 64 + lane];
    float ss = x0 * x0 + x1 * x1;
#pragma unroll
    for (int off = 1; off < 64; off <<= 1) ss += __shfl_xor(ss, off);
    float scale = rsqrtf(ss + 1e-6f);
    if (ch < 16) scale *= 0.08838834764831845f;  // DK^-0.5
    if (lane == 0) sc[ch] = scale;
  }
  __syncthreads();
  for (int c = tid; c < 2048; c += 256) {
    int h = c >> 7, d = c & 127;
    qn[((size_t)(b * NH + h) * S_LEN + s) * DKQ + d] = ys[c] * sc[h];
  }
  for (int c = tid; c < 512; c += 256) {
    int j = c >> 7, d = c & 127;
    kn[((size_t)(b * NKV + j) * S_LEN + s) * DKQ + d] = ys[2048 + c] * sc[16 + j];
    vn[((size_t)(b * NKV + j) * S_LEN + s) * DVV + d] = ys[2560 + c];
  }
}

// ---------------- phase A: per (bh, chunk of 64) — decays, L/P, forward substitution ----------------
// outputs per unit (stride 43008 B): P fp16 [64][64], W fp16 [64][128], Dloc fp16 [64][128],
// scalars f32: gam[64], gcr[64], gC
__global__ __launch_bounds__(256, 2) void phaseA_kernel(const float* __restrict__ qn,
                                                        const float* __restrict__ kn,
                                                        const float* __restrict__ vn,
                                                        const float* __restrict__ glog,
                                                        const float* __restrict__ be,
                                                        char* __restrict__ pout) {
  __shared__ _Float16 kh[64 * 136];
  __shared__ _Float16 qh[64 * 136];
  __shared__ float LT[64 * 68];   // LT[j][t] = L[t][j] (transposed, strictly-lower L)
  __shared__ float sc_c[64], sc_gam[64], sc_beta[64], sc_bg[64];

  int u = blockIdx.x;
  int bh = u >> 5, ch = u & 31;
  int t0 = ch * 64;
  int b = bh >> 4, h = bh & 15, kvh = h >> 2;
  const float* qb = qn + ((size_t)bh * S_LEN + t0) * DKQ;
  const float* kb = kn + (((size_t)(b * NKV + kvh)) * S_LEN + t0) * DKQ;
  const float* vb = vn + (((size_t)(b * NKV + kvh)) * S_LEN + t0) * DVV;
  const float* gl = glog + (size_t)bh * S_LEN + t0;
  const float* ber = be + (size_t)bh * S_LEN + t0;
  char* base = pout + (size_t)u * 43008;
  _Float16* P_out = (_Float16*)base;
  _Float16* W_out = (_Float16*)(base + 8192);
  _Float16* D_out = (_Float16*)(base + 24576);
  float* s_out = (float*)(base + 40960);

  int tid = threadIdx.x;
  // cumulative log-decay within chunk (wave 0)
  if (tid < 64) {
    float x = gl[tid];
#pragma unroll
    for (int off = 1; off < 64; off <<= 1) {
      float y = __shfl_up(x, off);
      if (tid >= off) x += y;
    }
    sc_c[tid] = x;
  }
  // stage k, q to LDS fp16
#pragma unroll
  for (int i = 0; i < 8; ++i) {
    int idx = i * 256 + tid;
    int t = idx >> 5, d4 = (idx & 31) * 4;
    float4 kv4 = *(const float4*)&kb[(size_t)t * DKQ + d4];
    float4 qv4 = *(const float4*)&qb[(size_t)t * DKQ + d4];
    _Float16* kd = &kh[t * 136 + d4];
    kd[0] = (_Float16)kv4.x; kd[1] = (_Float16)kv4.y; kd[2] = (_Float16)kv4.z; kd[3] = (_Float16)kv4.w;
    _Float16* qd = &qh[t * 136 + d4];
    qd[0] = (_Float16)qv4.x; qd[1] = (_Float16)qv4.y; qd[2] = (_Float16)qv4.z; qd[3] = (_Float16)qv4.w;
  }
  __syncthreads();
  if (tid < 64) {
    float c = sc_c[tid], c63 = sc_c[63];
    float gam = __expf(c);
    float bet = ber[tid];
    sc_gam[tid] = gam; sc_beta[tid] = bet; sc_bg[tid] = bet * gam;
    s_out[tid] = gam;
    s_out[64 + tid] = __expf(c63 - c);
    if (tid == 0) s_out[128] = __expf(c63);
  }
  __syncthreads();

  // z-init (global loads; overlap the MFMA below)
  float z[64];
  {
    const float* src = (tid < 128) ? vb : kb;
    const float* mult = (tid < 128) ? sc_beta : sc_bg;
    int col = tid & 127;
#pragma unroll
    for (int t = 0; t < 64; ++t) z[t] = mult[t] * src[(size_t)t * 128 + col];
  }

  // KK^T (waves 0,1) / QK^T (waves 2,3) via MFMA; 4 tiles each (16x16, K=128)
  int w = tid >> 6, l = tid & 63;
  int lr = l & 15, lk = (l >> 4) * 8, q4 = (l >> 4) * 4;
  floatx4 acc[8];
#pragma unroll
  for (int i = 0; i < 8; ++i) acc[i] = (floatx4){0.f, 0.f, 0.f, 0.f};
#pragma unroll
  for (int job = 0; job < 8; ++job) {
    int j2 = w * 8 + job;
    int tm = (j2 & 15) >> 2, tn = j2 & 3;
    const _Float16* Ar = (j2 < 16) ? kh : qh;
#pragma unroll
    for (int kk = 0; kk < 4; ++kk) {
      halfx8 af = *(const halfx8*)&Ar[(tm * 16 + lr) * 136 + kk * 32 + lk];
      halfx8 bf = *(const halfx8*)&kh[(tn * 16 + lr) * 136 + kk * 32 + lk];
      acc[job] = MFMA16(af, bf, acc[job]);
    }
  }
  // mask + decay; write LT (f32 LDS) and P (fp16 global)
#pragma unroll
  for (int job = 0; job < 8; ++job) {
    int j2 = w * 8 + job;
    int tm = (j2 & 15) >> 2, tn = j2 & 3;
    int jcol = tn * 16 + lr;
    float cj = sc_c[jcol];
#pragma unroll
    for (int r = 0; r < 4; ++r) {
      int trow = tm * 16 + q4 + r;
      float val = acc[job][r] * __expf(sc_c[trow] - cj);
      if (j2 < 16) {
        LT[jcol * 68 + trow] = (jcol < trow) ? sc_beta[trow] * val : 0.f;
      } else {
        P_out[trow * 64 + jcol] = (_Float16)((jcol <= trow) ? val : 0.f);
      }
    }
  }
  __syncthreads();

  // forward substitution (I+L) z = x, rank-1 update form; LT rows are wave-uniform broadcasts
#pragma unroll
  for (int t = 0; t < 64; ++t) {
    float zt = z[t];
    const int start = ((t + 1) >> 2) << 2;
#pragma unroll
    for (int t2 = start; t2 < 64; t2 += 4) {
      float4 lv = *(const float4*)&LT[t * 68 + t2];  // zero for t2 <= t
      z[t2 + 0] -= lv.x * zt;
      z[t2 + 1] -= lv.y * zt;
      z[t2 + 2] -= lv.z * zt;
      z[t2 + 3] -= lv.w * zt;
    }
  }
  // write Dloc (cols 0..127) / W (cols 0..127 from tid 128..255)
  {
    _Float16* Zo = (tid < 128) ? D_out : W_out;
    int col = tid & 127;
#pragma unroll
    for (int t = 0; t < 64; ++t) Zo[t * 128 + col] = (_Float16)z[t];
  }
}

// ---------------- phase B: per bh, serial over 32 chunks; S in MFMA accumulators ----------------
__global__ __launch_bounds__(256, 1) void phaseB_kernel(float* qo,  // qn region: read q, write o
                                                        const float* __restrict__ kn,
                                                        const char* __restrict__ pin) {
  __shared__ _Float16 Kt[128 * 72];   // K̂^T [dk][t]
  __shared__ _Float16 Wt[128 * 72];   // -W^T [v][t]
  __shared__ _Float16 Dt[128 * 72];   // Δ^T  [v][t]
  __shared__ _Float16 Ph[64 * 72];    // P    [t][j]
  __shared__ _Float16 St[128 * 136];  // S^T  [v][m]  (chunk-start state)
  __shared__ _Float16 Mh[128 * 136];  // M    [i][m]
  __shared__ _Float16 Eh[64 * 136];   // E    [t][m]
  __shared__ float gamS[64], gcrS[64], gCs[1];

  int bh = blockIdx.x;
  int b = bh >> 4, h = bh & 15, kvh = h >> 2;
  int tid = threadIdx.x, w = tid >> 6, l = tid & 63;
  int lr = l & 15, lk = (l >> 4) * 8, q4 = (l >> 4) * 4;

  floatx4 Sacc[2][8];
#pragma unroll
  for (int mi = 0; mi < 2; ++mi)
#pragma unroll
    for (int ni = 0; ni < 8; ++ni) Sacc[mi][ni] = (floatx4){0.f, 0.f, 0.f, 0.f};

  for (int c = 0; c < 32; ++c) {
    const char* base = pin + (size_t)(bh * 32 + c) * 43008;
    const _Float16* Pg = (const _Float16*)base;
    const _Float16* Wg = (const _Float16*)(base + 8192);
    const _Float16* Dg = (const _Float16*)(base + 24576);
    const float* sg = (const float*)(base + 40960);
    const float* qb = qo + ((size_t)bh * S_LEN + c * 64) * DKQ;
    const float* kb = kn + (((size_t)(b * NKV + kvh)) * S_LEN + c * 64) * DKQ;
    float* ob = qo + ((size_t)bh * S_LEN + c * 64) * DVV;

    __syncthreads();  // barD: prior chunk's MFMA LDS reads complete
    if (tid < 64) { gamS[tid] = sg[tid]; gcrS[tid] = sg[64 + tid]; }
    if (tid == 0) gCs[0] = sg[128];
    // stage S^T from accumulators (chunk-start state)
#pragma unroll
    for (int mi = 0; mi < 2; ++mi)
#pragma unroll
      for (int ni = 0; ni < 8; ++ni)
#pragma unroll
        for (int r = 0; r < 4; ++r)
          St[(ni * 16 + lr) * 136 + (w * 32 + mi * 16 + q4 + r)] = (_Float16)Sacc[mi][ni][r];
    __syncthreads();  // barA: St + scalars visible

    // stage Kt (scaled), Wt (negated), Dt, Ph
#pragma unroll
    for (int i = 0; i < 32; ++i) {
      int idx = i * 256 + tid;
      int t = idx >> 7, d = idx & 127;
      Kt[d * 72 + t] = (_Float16)(gcrS[t] * kb[(size_t)t * 128 + d]);
    }
#pragma unroll
    for (int i = 0; i < 32; ++i) {
      int idx = i * 256 + tid;
      int t = idx >> 7, v = idx & 127;
      Wt[v * 72 + t] = (_Float16)(-(float)Wg[t * 128 + v]);
      Dt[v * 72 + t] = Dg[t * 128 + v];
    }
#pragma unroll
    for (int i = 0; i < 16; ++i) {
      int idx = i * 256 + tid;
      int t = idx >> 6, j = idx & 63;
      Ph[t * 72 + j] = Pg[t * 64 + j];
    }
    // init accumulators: M = gC*I; B(Sacc)=0; E = Q̃ (gam_t * q); Oloc = 0
    floatx4 Macc[2][8], Eacc[8], Oacc[8];
    float gC = gCs[0];
#pragma unroll
    for (int mi = 0; mi < 2; ++mi)
#pragma unroll
      for (int ni = 0; ni < 8; ++ni) {
#pragma unroll
        for (int r = 0; r < 4; ++r)
          Macc[mi][ni][r] = ((w * 32 + mi * 16 + q4 + r) == (ni * 16 + lr)) ? gC : 0.f;
        Sacc[mi][ni] = (floatx4){0.f, 0.f, 0.f, 0.f};
      }
#pragma unroll
    for (int ni = 0; ni < 8; ++ni) {
      Oacc[ni] = (floatx4){0.f, 0.f, 0.f, 0.f};
#pragma unroll
      for (int r = 0; r < 4; ++r)
        Eacc[ni][r] = gamS[w * 16 + q4 + r] * qb[(size_t)(w * 16 + q4 + r) * 128 + ni * 16 + lr];
    }
    __syncthreads();  // barB: operands visible

    // builds (contract over t, K=64): M += K̂ᵀ(-W); B += K̂ᵀΔ; E += P(-W); Oloc += PΔ
#pragma unroll
    for (int ks = 0; ks < 2; ++ks) {
      halfx8 ka0 = *(const halfx8*)&Kt[(w * 32 + 0 + lr) * 72 + ks * 32 + lk];
      halfx8 ka1 = *(const halfx8*)&Kt[(w * 32 + 16 + lr) * 72 + ks * 32 + lk];
      halfx8 pa = *(const halfx8*)&Ph[(w * 16 + lr) * 72 + ks * 32 + lk];
#pragma unroll
      for (int ni = 0; ni < 8; ++ni) {
        halfx8 wb = *(const halfx8*)&Wt[(ni * 16 + lr) * 72 + ks * 32 + lk];
        halfx8 db = *(const halfx8*)&Dt[(ni * 16 + lr) * 72 + ks * 32 + lk];
        Macc[0][ni] = MFMA16(ka0, wb, Macc[0][ni]);
        Macc[1][ni] = MFMA16(ka1, wb, Macc[1][ni]);
        Sacc[0][ni] = MFMA16(ka0, db, Sacc[0][ni]);
        Sacc[1][ni] = MFMA16(ka1, db, Sacc[1][ni]);
        Eacc[ni] = MFMA16(pa, wb, Eacc[ni]);
        Oacc[ni] = MFMA16(pa, db, Oacc[ni]);
      }
    }
    // write Mh, Eh
#pragma unroll
    for (int mi = 0; mi < 2; ++mi)
#pragma unroll
      for (int ni = 0; ni < 8; ++ni)
#pragma unroll
        for (int r = 0; r < 4; ++r)
          Mh[(w * 32 + mi * 16 + q4 + r) * 136 + ni * 16 + lr] = (_Float16)Macc[mi][ni][r];
#pragma unroll
    for (int ni = 0; ni < 8; ++ni)
#pragma unroll
      for (int r = 0; r < 4; ++r)
        Eh[(w * 16 + q4 + r) * 136 + ni * 16 + lr] = (_Float16)Eacc[ni][r];
    __syncthreads();  // barC: Mh/Eh visible

    // S_new = M*S_old + B (Sacc holds B); O = E*S_old + Oloc  (contract over m, K=128)
#pragma unroll
    for (int ks = 0; ks < 4; ++ks) {
      halfx8 ma0 = *(const halfx8*)&Mh[(w * 32 + 0 + lr) * 136 + ks * 32 + lk];
      halfx8 ma1 = *(const halfx8*)&Mh[(w * 32 + 16 + lr) * 136 + ks * 32 + lk];
      halfx8 ea = *(const halfx8*)&Eh[(w * 16 + lr) * 136 + ks * 32 + lk];
#pragma unroll
      for (int ni = 0; ni < 8; ++ni) {
        halfx8 sb = *(const halfx8*)&St[(ni * 16 + lr) * 136 + ks * 32 + lk];
        Sacc[0][ni] = MFMA16(ma0, sb, Sacc[0][ni]);
        Sacc[1][ni] = MFMA16(ma1, sb, Sacc[1][ni]);
        Oacc[ni] = MFMA16(ea, sb, Oacc[ni]);
      }
    }
    // store O (rows of this chunk; same region rows as q we already consumed)
#pragma unroll
    for (int ni = 0; ni < 8; ++ni)
#pragma unroll
      for (int r = 0; r < 4; ++r)
        ob[(size_t)(w * 16 + q4 + r) * 128 + ni * 16 + lr] = Oacc[ni][r];
  }
}

// ---------------- per-head RMSNorm * out_norm_w * silu(g) -> og fp16 [M, H*DV] ----------------
__global__ __launch_bounds__(256) void normgate_kernel(const float* __restrict__ o_buf,
                                                       const float* __restrict__ g_buf,
                                                       const float* __restrict__ nw,
                                                       _Float16* __restrict__ og) {
  int gid = blockIdx.x * 4 + (threadIdx.x >> 6);
  int lane = threadIdx.x & 63;
  int m = gid >> 4, h = gid & 15;
  int b = m >> 11, s = m & (S_LEN - 1);
  const float* orow = o_buf + ((size_t)(b * NH + h) * S_LEN + s) * DVV;
  float o0 = orow[lane], o1 = orow[lane + 64];
  float ss = o0 * o0 + o1 * o1;
#pragma unroll
  for (int off = 1; off < 64; off <<= 1) ss += __shfl_xor(ss, off);
  float r = rsqrtf(ss * (1.f / 128.f) + 1e-5f);
  size_t gi = (size_t)m * HID + h * DVV;
  float g0 = g_buf[gi + lane], g1 = g_buf[gi + lane + 64];
  og[gi + lane] = (_Float16)(o0 * r * nw[lane] * (g0 * sigmoidf_(g0)));
  og[gi + lane + 64] = (_Float16)(o1 * r * nw[lane + 64] * (g1 * sigmoidf_(g1)));
}

extern "C" void kernel_launch(void* const* d_in, const int* in_sizes, int n_in,
                              void* d_out, int out_size, void* d_ws, size_t ws_size,
                              hipStream_t stream) {
  const float* X      = (const float*)d_in[0];
  const float* qkv_w  = (const float*)d_in[1];
  const float* g_w    = (const float*)d_in[2];
  const float* b_w    = (const float*)d_in[3];
  const float* gk_w   = (const float*)d_in[4];
  const float* conv_w = (const float*)d_in[5];
  const float* norm_w = (const float*)d_in[6];
  const float* o_w    = (const float*)d_in[7];
  float* out = (float*)d_out;

  char* ws = (char*)d_ws;
  float* qkv_buf   = (float*)(ws);                    // 0..50331648 (g_buf reuses first 32 MiB)
  _Float16* ow16   = (_Float16*)(ws + 33554432);      // free tail of qkv region after conv
  float* qn        = (float*)(ws + 50331648);         // 32 MiB; phase B reuses as o_buf
  float* kn        = (float*)(ws + 83886080);         // 8 MiB
  float* vn        = (float*)(ws + 92274688);         // 8 MiB
  float* glog      = (float*)(ws + 100663296);        // 0.25 MiB
  float* be        = (float*)(ws + 100925440);        // 0.25 MiB
  char*  pA        = (char*)(ws + 101449728);         // 42 MiB phase-A out (43008 * 1024)
  _Float16* X16    = (_Float16*)(ws + 101449728);     // dead before phase A writes
  _Float16* qw16   = (_Float16*)(ws + 118226944);     // dead after qkv GEMM
  _Float16* gw16   = (_Float16*)(ws + 130809856);     // dead after g GEMM
  _Float16* og16   = (_Float16*)(ws + 101449728);     // written post-phaseB (pA dead)
  float* g_buf     = qkv_buf;
  float* o_buf     = qn;

  dim3 blk(256);
  cvt_f16<<<dim3(4096), blk, 0, stream>>>(X, X16, 1048576);
  cvt_f16<<<dim3(3072), blk, 0, stream>>>(qkv_w, qw16, 786432);
  cvt_f16<<<dim3(2048), blk, 0, stream>>>(g_w, gw16, 524288);
  // 1) qkv projection
  gemm_bt_f16<<<dim3(QKV_DIM / 128, M_TOK / 128), blk, 0, stream>>>(X16, qw16, qkv_buf, M_TOK, QKV_DIM, HID);
  // 2) glog/beta
  gkb_kernel<<<dim3(M_TOK / 16), blk, 0, stream>>>(X, gk_w, b_w, glog, be);
  // 3) conv + silu + l2norm (consumes qkv_buf)
  conv_kernel<<<dim3(M_TOK), blk, 0, stream>>>(qkv_buf, conv_w, qn, kn, vn);
  // 4) o_w -> fp16 into freed tail of qkv region
  cvt_f16<<<dim3(2048), blk, 0, stream>>>(o_w, ow16, 524288);
  // 5) g projection (overwrites qkv_buf head)
  gemm_bt_f16<<<dim3(HID / 128, M_TOK / 128), blk, 0, stream>>>(X16, gw16, g_buf, M_TOK, HID, HID);
  // 6) chunked gated delta rule: phase A (parallel) + phase B (serial GEMM chain)
  phaseA_kernel<<<dim3(1024), blk, 0, stream>>>(qn, kn, vn, glog, be, pA);
  phaseB_kernel<<<dim3(32), blk, 0, stream>>>(qn, kn, pA);
  // 7) RMSNorm + gate -> og fp16
  normgate_kernel<<<dim3(M_TOK * NH / 4), blk, 0, stream>>>(o_buf, g_buf, norm_w, og16);
  // 8) output projection
  gemm_bt_f16<<<dim3(HID / 128, M_TOK / 128), blk, 0, stream>>>(og16, ow16, out, M_TOK, HID, HID);
}

// Round 5
// 617.409 us; speedup vs baseline: 2.7037x; 2.7037x over previous
//
#include <hip/hip_runtime.h>
#include <math.h>

#define S_LEN 2048
#define BATCH 2
#define NH 16
#define NKV 4
#define DKQ 128
#define DVV 128
#define HID 2048
#define QKV_DIM 3072
#define M_TOK 4096

typedef _Float16 halfx8 __attribute__((ext_vector_type(8)));
typedef _Float16 halfx4 __attribute__((ext_vector_type(4)));
typedef float floatx4 __attribute__((ext_vector_type(4)));

#define AS1 __attribute__((address_space(1)))
#define AS3 __attribute__((address_space(3)))
#define GLD16(gp, lp) __builtin_amdgcn_global_load_lds((AS1 const void*)(gp), (AS3 void*)(lp), 16, 0, 0)
#define MFMA16(a, b, c) __builtin_amdgcn_mfma_f32_16x16x32_f16(a, b, c, 0, 0, 0)

#define PA_STRIDE 81920  // per (bh,chunk): M 32768 | E 16384 | B 32768 (8 panels of [128][16])

__device__ __forceinline__ float sigmoidf_(float x) { return 1.f / (1.f + __expf(-x)); }

// ---------------- f32 -> f16 convert (8 elems/thread) ----------------
__global__ __launch_bounds__(256) void cvt_f16(const float* __restrict__ in,
                                               _Float16* __restrict__ out, int n8) {
  int i = blockIdx.x * 256 + threadIdx.x;
  if (i >= n8) return;
  const float4* p = (const float4*)in;
  float4 a = p[2 * (size_t)i], b = p[2 * (size_t)i + 1];
  halfx8 o;
  o[0] = (_Float16)a.x; o[1] = (_Float16)a.y; o[2] = (_Float16)a.z; o[3] = (_Float16)a.w;
  o[4] = (_Float16)b.x; o[5] = (_Float16)b.y; o[6] = (_Float16)b.z; o[7] = (_Float16)b.w;
  *(halfx8*)(out + (size_t)i * 8) = o;
}

// ---------------- fp16 MFMA GEMM NT: C[M,N] f32 = A[M,K] * B[N,K]^T ----------------
__global__ __launch_bounds__(256) void gemm_bt_f16(const _Float16* __restrict__ A,
                                                   const _Float16* __restrict__ B,
                                                   float* __restrict__ C,
                                                   int M, int N, int K) {
  __shared__ _Float16 As[128 * 32];
  __shared__ _Float16 Bs[128 * 32];
  int bm = blockIdx.y * 128, bn = blockIdx.x * 128;
  int tid = threadIdx.x;
  int w = tid >> 6, l = tid & 63;
  int wm = (w & 1) * 64, wn = (w >> 1) * 64;
  int lrow = l & 15, lk8 = (l >> 4) * 8;

  floatx4 zero = {0.f, 0.f, 0.f, 0.f};
  floatx4 acc[4][4];
#pragma unroll
  for (int i = 0; i < 4; ++i)
#pragma unroll
    for (int j = 0; j < 4; ++j) acc[i][j] = zero;

  const _Float16* ga = A + (size_t)(bm + (tid >> 2)) * K + (tid & 3) * 8;
  const _Float16* gb = B + (size_t)(bn + (tid >> 2)) * K + (tid & 3) * 8;
  _Float16* lA = As + w * 512;
  _Float16* lB = Bs + w * 512;

  for (int k0 = 0; k0 < K; k0 += 32) {
    GLD16(ga + k0, lA);
    GLD16(ga + k0 + (size_t)64 * K, lA + 2048);
    GLD16(gb + k0, lB);
    GLD16(gb + k0 + (size_t)64 * K, lB + 2048);
    __syncthreads();
    halfx8 af[4], bf_[4];
#pragma unroll
    for (int mi = 0; mi < 4; ++mi)
      af[mi] = *(const halfx8*)&As[(wm + mi * 16 + lrow) * 32 + lk8];
#pragma unroll
    for (int ni = 0; ni < 4; ++ni)
      bf_[ni] = *(const halfx8*)&Bs[(wn + ni * 16 + lrow) * 32 + lk8];
#pragma unroll
    for (int mi = 0; mi < 4; ++mi)
#pragma unroll
      for (int ni = 0; ni < 4; ++ni)
        acc[mi][ni] = MFMA16(af[mi], bf_[ni], acc[mi][ni]);
    __syncthreads();
  }
  int r0 = (l >> 4) * 4;
#pragma unroll
  for (int mi = 0; mi < 4; ++mi)
#pragma unroll
    for (int ni = 0; ni < 4; ++ni) {
      int col = bn + wn + ni * 16 + lrow;
#pragma unroll
      for (int r = 0; r < 4; ++r)
        C[(size_t)(bm + wm + mi * 16 + r0 + r) * N + col] = acc[mi][ni][r];
    }
}

// ---------------- gk/b projections -> glog [B,H,S] (= logsigmoid/16), beta [B,H,S] ----------------
__global__ __launch_bounds__(256) void gkb_kernel(const float* __restrict__ X,
                                                  const float* __restrict__ gk_w,
                                                  const float* __restrict__ b_w,
                                                  float* __restrict__ glog,
                                                  float* __restrict__ be) {
  __shared__ float xs[16][260];
  __shared__ float ws[32][260];
  int tid = threadIdx.x;
  int m0 = blockIdx.x * 16;
  int tl = tid >> 4, n0 = tid & 15;
  float acc0 = 0.f, acc1 = 0.f;
  for (int k0 = 0; k0 < HID; k0 += 256) {
#pragma unroll
    for (int i = 0; i < 4; ++i) {
      int F = i * 256 + tid;
      int r = F >> 6, c4 = (F & 63) * 4;
      *(float4*)&xs[r][c4] = *(const float4*)&X[(size_t)(m0 + r) * HID + k0 + c4];
    }
#pragma unroll
    for (int i = 0; i < 8; ++i) {
      int F = i * 256 + tid;
      int r = F >> 6, c4 = (F & 63) * 4;
      const float* src = (r < 16) ? (gk_w + (size_t)r * HID) : (b_w + (size_t)(r - 16) * HID);
      *(float4*)&ws[r][c4] = *(const float4*)&src[k0 + c4];
    }
    __syncthreads();
#pragma unroll 16
    for (int k = 0; k < 256; k += 4) {
      float4 a = *(const float4*)&xs[tl][k];
      float4 w0 = *(const float4*)&ws[n0][k];
      float4 w1 = *(const float4*)&ws[n0 + 16][k];
      acc0 += a.x * w0.x + a.y * w0.y + a.z * w0.z + a.w * w0.w;
      acc1 += a.x * w1.x + a.y * w1.y + a.z * w1.z + a.w * w1.w;
    }
    __syncthreads();
  }
  int m = m0 + tl, b = m >> 11, s = m & (S_LEN - 1);
  float z = acc0;
  float ls = (z >= 0.f) ? -log1pf(expf(-z)) : (z - log1pf(expf(z)));
  size_t oi = (size_t)(b * NH + n0) * S_LEN + s;
  glog[oi] = ls * 0.0625f;
  be[oi] = sigmoidf_(acc1);
}

// ---------------- causal dwconv(K=4)+SiLU, l2norm(q,k), q scale ----------------
__global__ __launch_bounds__(256) void conv_kernel(const float* __restrict__ qkv,
                                                   const float* __restrict__ conv_w,
                                                   float* __restrict__ qn,
                                                   float* __restrict__ kn,
                                                   float* __restrict__ vn) {
  __shared__ float ys[QKV_DIM];
  __shared__ float sc[20];
  int m = blockIdx.x;
  int b = m >> 11, s = m & (S_LEN - 1);
  int tid = threadIdx.x;
  for (int c = tid; c < QKV_DIM; c += 256) {
    float acc = 0.f;
#pragma unroll
    for (int i = 0; i < 4; ++i) {
      int si = s - 3 + i;
      if (si >= 0) acc += conv_w[c * 4 + i] * qkv[(size_t)(b * S_LEN + si) * QKV_DIM + c];
    }
    ys[c] = acc * (1.f / (1.f + __expf(-acc)));  // SiLU
  }
  __syncthreads();
  int wv = tid >> 6, lane = tid & 63;
  for (int ch = wv; ch < 20; ch += 4) {
    int base = (ch < 16) ? ch * 128 : 2048 + (ch - 16) * 128;
    float x0 = ys[base + lane], x1 = ys[base + 64 + lane];
    float ss = x0 * x0 + x1 * x1;
#pragma unroll
    for (int off = 1; off < 64; off <<= 1) ss += __shfl_xor(ss, off);
    float scale = rsqrtf(ss + 1e-6f);
    if (ch < 16) scale *= 0.08838834764831845f;  // DK^-0.5
    if (lane == 0) sc[ch] = scale;
  }
  __syncthreads();
  for (int c = tid; c < 2048; c += 256) {
    int h = c >> 7, d = c & 127;
    qn[((size_t)(b * NH + h) * S_LEN + s) * DKQ + d] = ys[c] * sc[h];
  }
  for (int c = tid; c < 512; c += 256) {
    int j = c >> 7, d = c & 127;
    kn[((size_t)(b * NKV + j) * S_LEN + s) * DKQ + d] = ys[2048 + c] * sc[16 + j];
    vn[((size_t)(b * NKV + j) * S_LEN + s) * DVV + d] = ys[2560 + c];
  }
}

// ---------------- phase A: per (bh, chunk of 64) — fully parallel ----------------
// Computes P,W,D (fwd substitution) then the chunk-local operators:
//   M = gC*I - K̂ᵀW, B = K̂ᵀΔ, E = Q̃ - PW, Oloc = PΔ
// M/E/B -> pA (fp16); Oloc -> obuf (f32, same rows as consumed q).
__global__ __launch_bounds__(256, 1) void phaseA_kernel(const float* __restrict__ qn,
                                                        const float* __restrict__ kn,
                                                        const float* __restrict__ vn,
                                                        const float* __restrict__ glog,
                                                        const float* __restrict__ be,
                                                        char* __restrict__ pout,
                                                        float* __restrict__ obuf) {
  __shared__ _Float16 kh[64 * 152];
  __shared__ _Float16 qh[64 * 152];
  __shared__ float LT[64 * 68];   // LT[j][t] = L[t][j]
  __shared__ _Float16 Kt[128 * 88];  // K̂ᵀ [dk][t]
  __shared__ _Float16 Wt[128 * 88];  // -Wᵀ [dk][t]
  __shared__ _Float16 Dt[128 * 88];  // Δᵀ  [dv][t]
  __shared__ _Float16 Ph[64 * 88];   // P   [t][j]
  __shared__ float sc_c[64], sc_beta[64], sc_gam[64], sc_bg[64], sc_gcr[64];

  int u = blockIdx.x;
  int bh = u >> 5, ch = u & 31;
  int t0 = ch * 64;
  int b = bh >> 4, h = bh & 15, kvh = h >> 2;
  const float* qb = qn + ((size_t)bh * S_LEN + t0) * DKQ;
  const float* kb = kn + (((size_t)(b * NKV + kvh)) * S_LEN + t0) * DKQ;
  const float* vb = vn + (((size_t)(b * NKV + kvh)) * S_LEN + t0) * DVV;
  const float* gl = glog + (size_t)bh * S_LEN + t0;
  const float* ber = be + (size_t)bh * S_LEN + t0;
  char* base = pout + (size_t)u * PA_STRIDE;
  _Float16* M_out = (_Float16*)base;
  _Float16* E_out = (_Float16*)(base + 32768);
  _Float16* B_out = (_Float16*)(base + 49152);
  float* ob = obuf + ((size_t)bh * S_LEN + t0) * DVV;

  int tid = threadIdx.x;
  if (tid < 64) {
    float x = gl[tid];
#pragma unroll
    for (int off = 1; off < 64; off <<= 1) {
      float y = __shfl_up(x, off);
      if (tid >= off) x += y;
    }
    sc_c[tid] = x;
  }
#pragma unroll
  for (int i = 0; i < 8; ++i) {
    int idx = i * 256 + tid;
    int t = idx >> 5, d4 = (idx & 31) * 4;
    float4 kv4 = *(const float4*)&kb[(size_t)t * DKQ + d4];
    float4 qv4 = *(const float4*)&qb[(size_t)t * DKQ + d4];
    _Float16* kd = &kh[t * 152 + d4];
    kd[0] = (_Float16)kv4.x; kd[1] = (_Float16)kv4.y; kd[2] = (_Float16)kv4.z; kd[3] = (_Float16)kv4.w;
    _Float16* qd = &qh[t * 152 + d4];
    qd[0] = (_Float16)qv4.x; qd[1] = (_Float16)qv4.y; qd[2] = (_Float16)qv4.z; qd[3] = (_Float16)qv4.w;
  }
  __syncthreads();
  if (tid < 64) {
    float c = sc_c[tid], c63 = sc_c[63];
    float gam = __expf(c);
    float bet = ber[tid];
    sc_gam[tid] = gam; sc_beta[tid] = bet; sc_bg[tid] = bet * gam;
    sc_gcr[tid] = __expf(c63 - c);
  }
  __syncthreads();

  // z init (global loads overlap the MFMA below)
  float z[64];
  {
    const float* src = (tid < 128) ? vb : kb;
    const float* mult = (tid < 128) ? sc_beta : sc_bg;
    int col = tid & 127;
#pragma unroll
    for (int t = 0; t < 64; ++t) z[t] = mult[t] * src[(size_t)t * 128 + col];
  }

  // KK^T (waves 0,1) / QK^T (waves 2,3) -> LT (f32 LDS) / Ph (fp16 LDS)
  int w = tid >> 6, l = tid & 63;
  int lr = l & 15, lk8 = (l >> 4) * 8, q4 = (l >> 4) * 4;
  floatx4 acc[8];
#pragma unroll
  for (int i = 0; i < 8; ++i) acc[i] = (floatx4){0.f, 0.f, 0.f, 0.f};
#pragma unroll
  for (int job = 0; job < 8; ++job) {
    int j2 = w * 8 + job;
    int tm = (j2 & 15) >> 2, tn = j2 & 3;
    const _Float16* Ar = (j2 < 16) ? kh : qh;
#pragma unroll
    for (int kk = 0; kk < 4; ++kk) {
      halfx8 af = *(const halfx8*)&Ar[(tm * 16 + lr) * 152 + kk * 32 + lk8];
      halfx8 bf = *(const halfx8*)&kh[(tn * 16 + lr) * 152 + kk * 32 + lk8];
      acc[job] = MFMA16(af, bf, acc[job]);
    }
  }
#pragma unroll
  for (int job = 0; job < 8; ++job) {
    int j2 = w * 8 + job;
    int tm = (j2 & 15) >> 2, tn = j2 & 3;
    int jcol = tn * 16 + lr;
    float cj = sc_c[jcol];
#pragma unroll
    for (int r = 0; r < 4; ++r) {
      int trow = tm * 16 + q4 + r;
      float val = acc[job][r] * __expf(sc_c[trow] - cj);
      if (j2 < 16) {
        LT[jcol * 68 + trow] = (jcol < trow) ? sc_beta[trow] * val : 0.f;
      } else {
        Ph[trow * 88 + jcol] = (_Float16)((jcol <= trow) ? val : 0.f);
      }
    }
  }
  __syncthreads();

  // forward substitution (I+L) z = x
#pragma unroll
  for (int t = 0; t < 64; ++t) {
    float zt = z[t];
    const int start = ((t + 1) >> 2) << 2;
#pragma unroll
    for (int t2 = start; t2 < 64; t2 += 4) {
      float4 lv = *(const float4*)&LT[t * 68 + t2];
      z[t2 + 0] -= lv.x * zt;
      z[t2 + 1] -= lv.y * zt;
      z[t2 + 2] -= lv.z * zt;
      z[t2 + 3] -= lv.w * zt;
    }
  }
  // Wt = -Wᵀ (tid>=128), Dt = Δᵀ (tid<128)
  {
    int col = tid & 127;
    if (tid < 128) {
#pragma unroll
      for (int t = 0; t < 64; ++t) Dt[col * 88 + t] = (_Float16)z[t];
    } else {
#pragma unroll
      for (int t = 0; t < 64; ++t) Wt[col * 88 + t] = (_Float16)(-z[t]);
    }
  }
  // Kt = K̂ᵀ (gcr-scaled)
#pragma unroll
  for (int i = 0; i < 32; ++i) {
    int idx = i * 256 + tid;
    int t = idx & 63, d = idx >> 6;
    Kt[d * 88 + t] = (_Float16)(sc_gcr[t] * (float)kh[t * 152 + d]);
  }
  __syncthreads();

  // builds: wave w -> M/B row-tiles {w*32, w*32+16}; E/Oloc t-tile w
  floatx4 Macc[2][8], Bacc[2][8], Eacc[8], Oacc[8];
  float gC = __expf(sc_c[63]);
#pragma unroll
  for (int mi = 0; mi < 2; ++mi)
#pragma unroll
    for (int ni = 0; ni < 8; ++ni) {
#pragma unroll
      for (int r = 0; r < 4; ++r)
        Macc[mi][ni][r] = ((w * 32 + mi * 16 + q4 + r) == (ni * 16 + lr)) ? gC : 0.f;
      Bacc[mi][ni] = (floatx4){0.f, 0.f, 0.f, 0.f};
    }
#pragma unroll
  for (int ni = 0; ni < 8; ++ni) {
    Oacc[ni] = (floatx4){0.f, 0.f, 0.f, 0.f};
#pragma unroll
    for (int r = 0; r < 4; ++r) {
      int trow = w * 16 + q4 + r;
      Eacc[ni][r] = sc_gam[trow] * (float)qh[trow * 152 + ni * 16 + lr];
    }
  }
#pragma unroll
  for (int ks = 0; ks < 2; ++ks) {
    halfx8 ka0 = *(const halfx8*)&Kt[(w * 32 + lr) * 88 + ks * 32 + lk8];
    halfx8 ka1 = *(const halfx8*)&Kt[(w * 32 + 16 + lr) * 88 + ks * 32 + lk8];
    halfx8 pa = *(const halfx8*)&Ph[(w * 16 + lr) * 88 + ks * 32 + lk8];
#pragma unroll
    for (int ni = 0; ni < 8; ++ni) {
      halfx8 wb = *(const halfx8*)&Wt[(ni * 16 + lr) * 88 + ks * 32 + lk8];
      halfx8 db = *(const halfx8*)&Dt[(ni * 16 + lr) * 88 + ks * 32 + lk8];
      Macc[0][ni] = MFMA16(ka0, wb, Macc[0][ni]);
      Macc[1][ni] = MFMA16(ka1, wb, Macc[1][ni]);
      Bacc[0][ni] = MFMA16(ka0, db, Bacc[0][ni]);
      Bacc[1][ni] = MFMA16(ka1, db, Bacc[1][ni]);
      Eacc[ni] = MFMA16(pa, wb, Eacc[ni]);
      Oacc[ni] = MFMA16(pa, db, Oacc[ni]);
    }
  }
  // outputs
#pragma unroll
  for (int mi = 0; mi < 2; ++mi)
#pragma unroll
    for (int ni = 0; ni < 8; ++ni)
#pragma unroll
      for (int r = 0; r < 4; ++r) {
        int row = w * 32 + mi * 16 + q4 + r;
        M_out[row * 128 + ni * 16 + lr] = (_Float16)Macc[mi][ni][r];
        B_out[ni * 2048 + row * 16 + lr] = (_Float16)Bacc[mi][ni][r];
      }
#pragma unroll
  for (int ni = 0; ni < 8; ++ni)
#pragma unroll
    for (int r = 0; r < 4; ++r) {
      int trow = w * 16 + q4 + r;
      E_out[trow * 128 + ni * 16 + lr] = (_Float16)Eacc[ni][r];
      ob[(size_t)trow * 128 + ni * 16 + lr] = Oacc[ni][r];
    }
}

// ---------------- phase B: 256 blocks (32 bh x 8 vgroups), serial over 32 chunks ----------------
// Per chunk: S <- M*S + B ; O = E*S + Oloc. M/E prefetched into double-buffered LDS.
__global__ __launch_bounds__(256, 1) void phaseB_kernel(const char* __restrict__ pin,
                                                        float* __restrict__ obuf) {
  __shared__ _Float16 Mh[2][128 * 152];
  __shared__ _Float16 Eh[2][64 * 152];
  __shared__ _Float16 St[16 * 152];

  int bh = blockIdx.x & 31, vg = blockIdx.x >> 5;  // same-bh blocks land on same XCD
  int tid = threadIdx.x, w = tid >> 6, l = tid & 63;
  int lr = l & 15, lk8 = (l >> 4) * 8, q4 = (l >> 4) * 4;
  const char* ub0 = pin + (size_t)(bh * 32) * PA_STRIDE;
  float* ob_base = obuf + (size_t)bh * S_LEN * DVV + vg * 16;

  float4 Mr[8], Er[4];
  float Bc[2][4], Oc[4], Bn[2][4], On[4];

  // chunk 0 operands
  {
    const float4* Mg = (const float4*)ub0;
    const float4* Eg = (const float4*)(ub0 + 32768);
    const _Float16* Bg = (const _Float16*)(ub0 + 49152) + vg * 2048;
#pragma unroll
    for (int j = 0; j < 8; ++j) Mr[j] = Mg[j * 256 + tid];
#pragma unroll
    for (int j = 0; j < 4; ++j) Er[j] = Eg[j * 256 + tid];
#pragma unroll
    for (int mi = 0; mi < 2; ++mi)
#pragma unroll
      for (int r = 0; r < 4; ++r)
        Bc[mi][r] = (float)Bg[(w * 32 + mi * 16 + q4 + r) * 16 + lr];
#pragma unroll
    for (int r = 0; r < 4; ++r)
      Oc[r] = ob_base[(size_t)(w * 16 + q4 + r) * DVV + lr];
#pragma unroll
    for (int j = 0; j < 8; ++j) {
      int n = j * 256 + tid;
      *(float4*)&Mh[0][(n >> 4) * 152 + (n & 15) * 8] = Mr[j];
    }
#pragma unroll
    for (int j = 0; j < 4; ++j) {
      int n = j * 256 + tid;
      *(float4*)&Eh[0][(n >> 4) * 152 + (n & 15) * 8] = Er[j];
    }
  }
  __syncthreads();

  floatx4 Sacc[2];
  Sacc[0] = (floatx4){0.f, 0.f, 0.f, 0.f};
  Sacc[1] = (floatx4){0.f, 0.f, 0.f, 0.f};

  for (int c = 0; c < 32; ++c) {
    int cur = c & 1;
    bool have = (c + 1) < 32;
    // prefetch chunk c+1 (independent of serial chain)
    if (have) {
      const char* un = ub0 + (size_t)(c + 1) * PA_STRIDE;
      const float4* Mg = (const float4*)un;
      const float4* Eg = (const float4*)(un + 32768);
      const _Float16* Bg = (const _Float16*)(un + 49152) + vg * 2048;
#pragma unroll
      for (int j = 0; j < 8; ++j) Mr[j] = Mg[j * 256 + tid];
#pragma unroll
      for (int j = 0; j < 4; ++j) Er[j] = Eg[j * 256 + tid];
#pragma unroll
      for (int mi = 0; mi < 2; ++mi)
#pragma unroll
        for (int r = 0; r < 4; ++r)
          Bn[mi][r] = (float)Bg[(w * 32 + mi * 16 + q4 + r) * 16 + lr];
#pragma unroll
      for (int r = 0; r < 4; ++r)
        On[r] = ob_base[(size_t)((c + 1) * 64 + w * 16 + q4 + r) * DVV + lr];
    }
    // stage S^T (state at chunk start) to LDS
#pragma unroll
    for (int mi = 0; mi < 2; ++mi) {
      halfx4 sv;
#pragma unroll
      for (int r = 0; r < 4; ++r) sv[r] = (_Float16)Sacc[mi][r];
      *(halfx4*)&St[lr * 152 + w * 32 + mi * 16 + q4] = sv;
    }
    __syncthreads();
    // S_new = M*S + B ; O = E*S + Oloc
    floatx4 Sn0 = {Bc[0][0], Bc[0][1], Bc[0][2], Bc[0][3]};
    floatx4 Sn1 = {Bc[1][0], Bc[1][1], Bc[1][2], Bc[1][3]};
    floatx4 Oa = {Oc[0], Oc[1], Oc[2], Oc[3]};
#pragma unroll
    for (int ks = 0; ks < 4; ++ks) {
      halfx8 sf = *(const halfx8*)&St[lr * 152 + ks * 32 + lk8];
      halfx8 ma0 = *(const halfx8*)&Mh[cur][(w * 32 + lr) * 152 + ks * 32 + lk8];
      halfx8 ma1 = *(const halfx8*)&Mh[cur][(w * 32 + 16 + lr) * 152 + ks * 32 + lk8];
      halfx8 ea = *(const halfx8*)&Eh[cur][(w * 16 + lr) * 152 + ks * 32 + lk8];
      Sn0 = MFMA16(ma0, sf, Sn0);
      Sn1 = MFMA16(ma1, sf, Sn1);
      Oa = MFMA16(ea, sf, Oa);
    }
    // store O for this chunk
    {
      float* obr = ob_base + (size_t)c * 64 * DVV;
#pragma unroll
      for (int r = 0; r < 4; ++r)
        obr[(size_t)(w * 16 + q4 + r) * DVV + lr] = Oa[r];
    }
    Sacc[0] = Sn0; Sacc[1] = Sn1;
    // write prefetched operands into other buffer
    if (have) {
      int nb = cur ^ 1;
#pragma unroll
      for (int j = 0; j < 8; ++j) {
        int n = j * 256 + tid;
        *(float4*)&Mh[nb][(n >> 4) * 152 + (n & 15) * 8] = Mr[j];
      }
#pragma unroll
      for (int j = 0; j < 4; ++j) {
        int n = j * 256 + tid;
        *(float4*)&Eh[nb][(n >> 4) * 152 + (n & 15) * 8] = Er[j];
      }
#pragma unroll
      for (int mi = 0; mi < 2; ++mi)
#pragma unroll
        for (int r = 0; r < 4; ++r) Bc[mi][r] = Bn[mi][r];
#pragma unroll
      for (int r = 0; r < 4; ++r) Oc[r] = On[r];
    }
    __syncthreads();
  }
}

// ---------------- per-head RMSNorm * out_norm_w * silu(g) -> og fp16 [M, H*DV] ----------------
__global__ __launch_bounds__(256) void normgate_kernel(const float* __restrict__ o_buf,
                                                       const float* __restrict__ g_buf,
                                                       const float* __restrict__ nw,
                                                       _Float16* __restrict__ og) {
  int gid = blockIdx.x * 4 + (threadIdx.x >> 6);
  int lane = threadIdx.x & 63;
  int m = gid >> 4, h = gid & 15;
  int b = m >> 11, s = m & (S_LEN - 1);
  const float* orow = o_buf + ((size_t)(b * NH + h) * S_LEN + s) * DVV;
  float o0 = orow[lane], o1 = orow[lane + 64];
  float ss = o0 * o0 + o1 * o1;
#pragma unroll
  for (int off = 1; off < 64; off <<= 1) ss += __shfl_xor(ss, off);
  float r = rsqrtf(ss * (1.f / 128.f) + 1e-5f);
  size_t gi = (size_t)m * HID + h * DVV;
  float g0 = g_buf[gi + lane], g1 = g_buf[gi + lane + 64];
  og[gi + lane] = (_Float16)(o0 * r * nw[lane] * (g0 * sigmoidf_(g0)));
  og[gi + lane + 64] = (_Float16)(o1 * r * nw[lane + 64] * (g1 * sigmoidf_(g1)));
}

extern "C" void kernel_launch(void* const* d_in, const int* in_sizes, int n_in,
                              void* d_out, int out_size, void* d_ws, size_t ws_size,
                              hipStream_t stream) {
  const float* X      = (const float*)d_in[0];
  const float* qkv_w  = (const float*)d_in[1];
  const float* g_w    = (const float*)d_in[2];
  const float* b_w    = (const float*)d_in[3];
  const float* gk_w   = (const float*)d_in[4];
  const float* conv_w = (const float*)d_in[5];
  const float* norm_w = (const float*)d_in[6];
  const float* o_w    = (const float*)d_in[7];
  float* out = (float*)d_out;

  char* ws = (char*)d_ws;
  // lifetimes: qkv_buf [gemm_qkv..conv]; g_buf [gemm_g..normgate]; pA [phaseA..phaseB];
  // X16 [cvt..gemm_g]; qw16 [cvt..gemm_qkv]; gw16 [cvt..gemm_g]; og16 [normgate..gemm_out]
  float* qkv_buf   = (float*)(ws);                    // [0, 50331648)
  float* g_buf     = (float*)(ws);                    // [0, 33554432) after phaseB? no: gemm_g before phaseA; region disjoint from pA
  _Float16* ow16   = (_Float16*)(ws + 33554432);      // [33554432, 41943040) written after conv
  float* glog      = (float*)(ws + 41943040);         // written after conv (qkv tail dead)
  float* be        = (float*)(ws + 42205184);
  float* qn        = (float*)(ws + 50331648);         // [50331648, 83886080); obuf reuses
  float* kn        = (float*)(ws + 83886080);         // 8 MiB
  float* vn        = (float*)(ws + 92274688);         // 8 MiB
  _Float16* X16    = (_Float16*)(ws + 100663296);     // 16 MiB, dead before phaseA
  _Float16* qw16   = (_Float16*)(ws + 117440512);     // 12 MiB, dead after gemm_qkv
  _Float16* gw16   = (_Float16*)(ws + 130023424);     // 8 MiB, dead after gemm_g
  char*  pA        = (char*)(ws + 100663296);         // 80 MiB [100663296, 184549376)
  _Float16* og16   = (_Float16*)(ws + 100663296);     // reuse pA after phaseB
  float* o_buf     = qn;

  dim3 blk(256);
  cvt_f16<<<dim3(4096), blk, 0, stream>>>(X, X16, 1048576);
  cvt_f16<<<dim3(3072), blk, 0, stream>>>(qkv_w, qw16, 786432);
  cvt_f16<<<dim3(2048), blk, 0, stream>>>(g_w, gw16, 524288);
  // 1) qkv projection
  gemm_bt_f16<<<dim3(QKV_DIM / 128, M_TOK / 128), blk, 0, stream>>>(X16, qw16, qkv_buf, M_TOK, QKV_DIM, HID);
  // 2) conv + silu + l2norm (consumes qkv_buf)
  conv_kernel<<<dim3(M_TOK), blk, 0, stream>>>(qkv_buf, conv_w, qn, kn, vn);
  // 3) glog/beta + o_w cvt (into freed qkv region)
  gkb_kernel<<<dim3(M_TOK / 16), blk, 0, stream>>>(X, gk_w, b_w, glog, be);
  cvt_f16<<<dim3(2048), blk, 0, stream>>>(o_w, ow16, 524288);
  // 4) g projection (overwrites qkv_buf head; X16/gw16 die here)
  gemm_bt_f16<<<dim3(HID / 128, M_TOK / 128), blk, 0, stream>>>(X16, gw16, g_buf, M_TOK, HID, HID);
  // 5) chunked gated delta rule
  phaseA_kernel<<<dim3(1024), blk, 0, stream>>>(qn, kn, vn, glog, be, pA, o_buf);
  phaseB_kernel<<<dim3(256), blk, 0, stream>>>(pA, o_buf);
  // 6) RMSNorm + gate -> og fp16 (pA dead)
  normgate_kernel<<<dim3(M_TOK * NH / 4), blk, 0, stream>>>(o_buf, g_buf, norm_w, og16);
  // 7) output projection
  gemm_bt_f16<<<dim3(HID / 128, M_TOK / 128), blk, 0, stream>>>(og16, ow16, out, M_TOK, HID, HID);
}